// Round 3
// baseline (3778.806 us; speedup 1.0000x reference)
//
#include <hip/hip_runtime.h>

#define B_    64
#define T_    512
#define D_    512
#define KF    1024      // fused K = [h(512) ; x(512)]
#define NGRP  4         // batch groups
#define NSLC  16        // WG slices per group
#define GB    16        // batches per group

using short8 = __attribute__((ext_vector_type(8))) short;
using f32x4  = __attribute__((ext_vector_type(4))) float;

__device__ __forceinline__ unsigned short f2bf(float f) {
    unsigned int u = __float_as_uint(f);
    u = (u + 0x7fffu + ((u >> 16) & 1u)) >> 16;
    return (unsigned short)u;
}
__device__ __forceinline__ float sigmf(float x)  { return 1.0f / (1.0f + __expf(-x)); }
__device__ __forceinline__ float tanh_f(float x) { return 1.0f - 2.0f / (1.0f + __expf(2.0f * x)); }

// ---- prep: X fp32 -> bf16 ----
__global__ void prep_x(const float* __restrict__ X, unsigned short* __restrict__ Xb, int n4) {
    int stride = gridDim.x * blockDim.x;
    for (int i = blockIdx.x * blockDim.x + threadIdx.x; i < n4; i += stride) {
        float4 v = ((const float4*)X)[i];
        ushort4 o;
        o.x = f2bf(v.x); o.y = f2bf(v.y); o.z = f2bf(v.z); o.w = f2bf(v.w);
        ((ushort4*)Xb)[i] = o;
    }
}

// ---- prep: fused weight Wcat[r = o*4+g][k]; gate g: 0=i(Ui,Wi) 1=f(Uf,Wi quirk) 2=c(Uc,Wc) 3=o(Uo,Wo)
__global__ void prep_w(const float* __restrict__ Wi, const float* __restrict__ Wc,
                       const float* __restrict__ Wo,
                       const float* __restrict__ Ui, const float* __restrict__ Uf,
                       const float* __restrict__ Uc, const float* __restrict__ Uo,
                       unsigned short* __restrict__ Wcat) {
    int idx = blockIdx.x * blockDim.x + threadIdx.x;
    if (idx >= 2048 * 1024) return;
    int r = idx >> 10, k = idx & 1023;
    int o = r >> 2, g = r & 3;
    const float* U = (g == 0) ? Ui : (g == 1) ? Uf : (g == 2) ? Uc : Uo;
    const float* W = (g < 2) ? Wi : (g == 2) ? Wc : Wo;
    float v = (k < 512) ? U[o * 512 + k] : W[o * 512 + (k - 512)];
    Wcat[idx] = f2bf(v);
}

// ---- persistent recurrence kernel, wave-specialized ----
// 64 WGs: group g = bid>>4 (16 batches), slice s = bid&15 (128 gate-rows = 32 ocols)
// waves 0-3: H-role (U-half, K in [0,512))   -- critical path
// waves 4-7: X-role (W-half, K in [512,1024)) -- runs ahead via Sp ring
__launch_bounds__(512, 2)
__global__ void lstm_rec(const unsigned short* __restrict__ Xb,
                         const unsigned short* __restrict__ Wcat,
                         unsigned short* __restrict__ hbuf,   // [2][64][512] bf16
                         unsigned int* __restrict__ cnt,      // [NGRP][T_]
                         float* __restrict__ out,             // H then C (fp32)
                         const float* __restrict__ bi, const float* __restrict__ bc,
                         const float* __restrict__ bo, const float* __restrict__ bUf,
                         const float* __restrict__ bUc, const float* __restrict__ bUo) {
    __shared__ float Sp[2][8][16][20];          // [slot][tile][batch][4 gates x q, pad 20]
    __shared__ unsigned int xready[2];          // monotonic: X-wave completions per slot
    __shared__ unsigned int hdone[2];           // monotonic: H-wave consumptions per slot
    __shared__ unsigned int hsync;              // monotonic: H-wave store-drain count

    const int tid  = threadIdx.x;
    const int bid  = blockIdx.x;
    const int g    = bid >> 4;
    const int s    = bid & 15;
    const int wave = tid >> 6;
    const int lane = tid & 63;
    const int q    = lane >> 4;
    const int bl   = lane & 15;
    const int mp   = wave & 3;
    const bool isH = (wave < 4);

    if (tid == 0) { xready[0] = xready[1] = 0u; hdone[0] = hdone[1] = 0u; hsync = 0u; }
    __syncthreads();

    // ---- one-time: this wave's weight fragments (2 M-tiles x 16 ksteps x 4 VGPR = 128) ----
    short8 Wf0[16], Wf1[16];
    {
        const int r0   = s * 128 + mp * 32;
        const int kofs = (isH ? 0 : 512) + q * 8;
        #pragma unroll
        for (int kt = 0; kt < 16; ++kt) {
            Wf0[kt] = *(const short8*)(Wcat + (size_t)(r0 + bl) * KF + kofs + kt * 32);
            Wf1[kt] = *(const short8*)(Wcat + (size_t)(r0 + 16 + bl) * KF + kofs + kt * 32);
        }
    }

    if (!isH) {
        // ================= X-role: free-running, bounded by Sp ring =================
        const unsigned short* xrow = Xb + (size_t)(g * GB + bl) * T_ * D_ + q * 8;
        for (int t = 0; t < T_; ++t) {
            #pragma unroll
            for (int i = 0; i < 16; ++i) asm volatile("" : "+v"(Wf0[i]), "+v"(Wf1[i]));
            const int slot = t & 1;
            if (t >= 2 && lane == 0) {
                const unsigned int need = 4u * (unsigned)(t >> 1);
                while (__hip_atomic_load(&hdone[slot], __ATOMIC_ACQUIRE, __HIP_MEMORY_SCOPE_WORKGROUP) < need) { }
            }
            f32x4 a0 = {0.f, 0.f, 0.f, 0.f};
            f32x4 a1 = {0.f, 0.f, 0.f, 0.f};
            const unsigned short* xp = xrow + (size_t)t * D_;
            #pragma unroll
            for (int kt = 0; kt < 16; ++kt) {
                short8 b = *(const short8*)(xp + kt * 32);
                a0 = __builtin_amdgcn_mfma_f32_16x16x32_bf16(Wf0[kt], b, a0, 0, 0, 0);
                a1 = __builtin_amdgcn_mfma_f32_16x16x32_bf16(Wf1[kt], b, a1, 0, 0, 0);
            }
            *(f32x4*)&Sp[slot][mp * 2 + 0][bl][q * 4] = a0;
            *(f32x4*)&Sp[slot][mp * 2 + 1][bl][q * 4] = a1;
            if (lane == 0)
                __hip_atomic_fetch_add(&xready[slot], 1u, __ATOMIC_RELEASE, __HIP_MEMORY_SCOPE_WORKGROUP);
        }
    } else {
        // ================= H-role: the critical path =================
        unsigned int* gfl = cnt + (size_t)g * T_;
        const int ogq = s * 32 + mp * 8 + q;
        const float bi0  = bi[ogq],     bf0v = bi[ogq] + bUf[ogq];
        const float bc0v = bc[ogq] + bUc[ogq], bo0v = bo[ogq] + bUo[ogq];
        const float bi1  = bi[ogq + 4], bf1v = bi[ogq + 4] + bUf[ogq + 4];
        const float bc1v = bc[ogq + 4] + bUc[ogq + 4], bo1v = bo[ogq + 4] + bUo[ogq + 4];
        float c0s = 0.f, c1s = 0.f;
        float* Hout = out;
        float* Cout = out + (size_t)B_ * T_ * D_;

        for (int t = 0; t < T_; ++t) {
            #pragma unroll
            for (int i = 0; i < 16; ++i) asm volatile("" : "+v"(Wf0[i]), "+v"(Wf1[i]));
            const int slot = t & 1, prev = slot ^ 1;

            // wait for h_{t-1} globally visible (lane0 spins, wave blocks at reconvergence)
            if (t > 0 && lane == 0) {
                while (__hip_atomic_load(gfl + (t - 1), __ATOMIC_RELAXED, __HIP_MEMORY_SCOPE_AGENT) < NSLC) { }
            }
            asm volatile("" ::: "memory");

            // direct B-fragment loads of h (coherent), 4 interleaved MFMA chains
            const unsigned long long* hp =
                (const unsigned long long*)(hbuf + ((size_t)prev * B_ + g * GB + bl) * D_ + q * 8);
            f32x4 e0 = {0.f,0.f,0.f,0.f}, e1 = {0.f,0.f,0.f,0.f};
            f32x4 o0 = {0.f,0.f,0.f,0.f}, o1 = {0.f,0.f,0.f,0.f};
            #pragma unroll
            for (int kt = 0; kt < 16; kt += 2) {
                union { unsigned long long u[2]; short8 v; } cb0, cb1;
                cb0.u[0] = __hip_atomic_load(hp + kt * 8,     __ATOMIC_RELAXED, __HIP_MEMORY_SCOPE_AGENT);
                cb0.u[1] = __hip_atomic_load(hp + kt * 8 + 1, __ATOMIC_RELAXED, __HIP_MEMORY_SCOPE_AGENT);
                cb1.u[0] = __hip_atomic_load(hp + kt * 8 + 8, __ATOMIC_RELAXED, __HIP_MEMORY_SCOPE_AGENT);
                cb1.u[1] = __hip_atomic_load(hp + kt * 8 + 9, __ATOMIC_RELAXED, __HIP_MEMORY_SCOPE_AGENT);
                e0 = __builtin_amdgcn_mfma_f32_16x16x32_bf16(Wf0[kt],     cb0.v, e0, 0, 0, 0);
                e1 = __builtin_amdgcn_mfma_f32_16x16x32_bf16(Wf1[kt],     cb0.v, e1, 0, 0, 0);
                o0 = __builtin_amdgcn_mfma_f32_16x16x32_bf16(Wf0[kt + 1], cb1.v, o0, 0, 0, 0);
                o1 = __builtin_amdgcn_mfma_f32_16x16x32_bf16(Wf1[kt + 1], cb1.v, o1, 0, 0, 0);
            }

            // wait X-partials for this step, then merge
            if (lane == 0) {
                const unsigned int need = 4u * (unsigned)((t >> 1) + 1);
                while (__hip_atomic_load(&xready[slot], __ATOMIC_ACQUIRE, __HIP_MEMORY_SCOPE_WORKGROUP) < need) { }
            }
            f32x4 sp0 = *(const f32x4*)&Sp[slot][mp * 2 + 0][bl][q * 4];
            f32x4 sp1 = *(const f32x4*)&Sp[slot][mp * 2 + 1][bl][q * 4];
            f32x4 A0 = (e0 + o0) + sp0;
            f32x4 A1 = (e1 + o1) + sp1;
            // Sp values consumed into registers (use forces lgkmcnt drain) -> release slot
            if (lane == 0)
                __hip_atomic_fetch_add(&hdone[slot], 1u, __ATOMIC_RELAXED, __HIP_MEMORY_SCOPE_WORKGROUP);

            // elementwise gates: lane owns (ocol ogq, batch bl) and (ogq+4, bl)
            float iv = sigmf(A0[0] + bi0);
            float fv = sigmf(A0[1] + bf0v);
            float cc = tanh_f(A0[2] + bc0v);
            float ov = sigmf(A0[3] + bo0v);
            float cn0 = fv * c0s + iv * cc;
            float hv0 = ov * tanh_f(cn0);
            c0s = cn0;
            iv = sigmf(A1[0] + bi1);
            fv = sigmf(A1[1] + bf1v);
            cc = tanh_f(A1[2] + bc1v);
            ov = sigmf(A1[3] + bo1v);
            float cn1 = fv * c1s + iv * cc;
            float hv1 = ov * tanh_f(cn1);
            c1s = cn1;

            // h -> hbuf (bf16, coherent scatter stores), drain, signal
            unsigned short* hd = hbuf + ((size_t)slot * B_ + g * GB + bl) * D_ + ogq;
            __hip_atomic_store(hd,     f2bf(hv0), __ATOMIC_RELAXED, __HIP_MEMORY_SCOPE_AGENT);
            __hip_atomic_store(hd + 4, f2bf(hv1), __ATOMIC_RELAXED, __HIP_MEMORY_SCOPE_AGENT);
            asm volatile("s_waitcnt vmcnt(0)" ::: "memory");
            if (lane == 0)
                __hip_atomic_fetch_add(&hsync, 1u, __ATOMIC_RELAXED, __HIP_MEMORY_SCOPE_WORKGROUP);
            if (wave == 0 && lane == 0) {
                while (__hip_atomic_load(&hsync, __ATOMIC_RELAXED, __HIP_MEMORY_SCOPE_WORKGROUP) < 4u * (unsigned)(t + 1)) { }
                __hip_atomic_fetch_add(gfl + t, 1u, __ATOMIC_RELAXED, __HIP_MEMORY_SCOPE_AGENT);
            }

            // streaming outputs, off the flag-critical path
            const size_t oi = ((size_t)(g * GB + bl) * T_ + t) * D_ + ogq;
            __builtin_nontemporal_store(hv0, Hout + oi);
            __builtin_nontemporal_store(hv1, Hout + oi + 4);
            __builtin_nontemporal_store(cn0, Cout + oi);
            __builtin_nontemporal_store(cn1, Cout + oi + 4);
        }
    }
}

extern "C" void kernel_launch(void* const* d_in, const int* in_sizes, int n_in,
                              void* d_out, int out_size, void* d_ws, size_t ws_size,
                              hipStream_t stream) {
    const float* X   = (const float*)d_in[0];
    const float* Wi  = (const float*)d_in[1];
    const float* bi  = (const float*)d_in[2];
    // d_in[3] = Wf, d_in[4] = bf : unused by reference semantics
    const float* Wc  = (const float*)d_in[5];
    const float* bc  = (const float*)d_in[6];
    const float* Wo  = (const float*)d_in[7];
    const float* bo  = (const float*)d_in[8];
    const float* Ui  = (const float*)d_in[9];
    const float* Uf  = (const float*)d_in[10];
    const float* bUf = (const float*)d_in[11];
    const float* Uc  = (const float*)d_in[12];
    const float* bUc = (const float*)d_in[13];
    const float* Uo  = (const float*)d_in[14];
    const float* bUo = (const float*)d_in[15];

    char* ws = (char*)d_ws;
    const size_t XB_BYTES   = (size_t)B_ * T_ * D_ * 2;   // 33,554,432
    const size_t WCAT_BYTES = (size_t)2048 * 1024 * 2;    //  4,194,304
    const size_t HBUF_BYTES = (size_t)2 * B_ * D_ * 2;    //    131,072 (bf16)
    const size_t CNT_BYTES  = (size_t)NGRP * T_ * 4;      //      8,192

    unsigned short* Xb   = (unsigned short*)ws;
    unsigned short* Wcat = (unsigned short*)(ws + XB_BYTES);
    unsigned short* hbuf = (unsigned short*)(ws + XB_BYTES + WCAT_BYTES);
    unsigned int*   cnt  = (unsigned int*)(ws + XB_BYTES + WCAT_BYTES + HBUF_BYTES);

    // zero h (t=0 reads buffer 1) and the per-step flags, every call
    hipMemsetAsync(hbuf, 0, HBUF_BYTES + CNT_BYTES, stream);

    prep_x<<<2048, 256, 0, stream>>>(X, Xb, B_ * T_ * D_ / 4);
    prep_w<<<8192, 256, 0, stream>>>(Wi, Wc, Wo, Ui, Uf, Uc, Uo, Wcat);
    lstm_rec<<<NGRP * NSLC, 512, 0, stream>>>(Xb, Wcat, hbuf, cnt, (float*)d_out,
                                              bi, bc, bo, bUf, bUc, bUo);
}

// Round 4
// 3330.279 us; speedup vs baseline: 1.1347x; 1.1347x over previous
//
#include <hip/hip_runtime.h>

#define B_    64
#define T_    512
#define D_    512
#define KF    1024      // fused weight K = [h(512) ; x(512)]
#define NGRP  4         // batch groups
#define NSLC  32        // WG slices per group
#define GB    16        // batches per group

using short8 = __attribute__((ext_vector_type(8))) short;
using f32x4  = __attribute__((ext_vector_type(4))) float;

__device__ __forceinline__ unsigned short f2bf(float f) {
    unsigned int u = __float_as_uint(f);
    u = (u + 0x7fffu + ((u >> 16) & 1u)) >> 16;
    return (unsigned short)u;
}
__device__ __forceinline__ float sigmf(float x)  { return 1.0f / (1.0f + __expf(-x)); }
__device__ __forceinline__ float tanh_f(float x) { return 1.0f - 2.0f / (1.0f + __expf(2.0f * x)); }

// ---- prep: X fp32 -> bf16 ----
__global__ void prep_x(const float* __restrict__ X, unsigned short* __restrict__ Xb, int n4) {
    int stride = gridDim.x * blockDim.x;
    for (int i = blockIdx.x * blockDim.x + threadIdx.x; i < n4; i += stride) {
        float4 v = ((const float4*)X)[i];
        ushort4 o;
        o.x = f2bf(v.x); o.y = f2bf(v.y); o.z = f2bf(v.z); o.w = f2bf(v.w);
        ((ushort4*)Xb)[i] = o;
    }
}

// ---- prep: fused weight Wcat[r = o*4+g][k]; gate g: 0=i(Ui,Wi) 1=f(Uf,Wi quirk) 2=c(Uc,Wc) 3=o(Uo,Wo)
__global__ void prep_w(const float* __restrict__ Wi, const float* __restrict__ Wc,
                       const float* __restrict__ Wo,
                       const float* __restrict__ Ui, const float* __restrict__ Uf,
                       const float* __restrict__ Uc, const float* __restrict__ Uo,
                       unsigned short* __restrict__ Wcat) {
    int idx = blockIdx.x * blockDim.x + threadIdx.x;
    if (idx >= 2048 * 1024) return;
    int r = idx >> 10, k = idx & 1023;
    int o = r >> 2, g = r & 3;
    const float* U = (g == 0) ? Ui : (g == 1) ? Uf : (g == 2) ? Uc : Uo;
    const float* W = (g < 2) ? Wi : (g == 2) ? Wc : Wo;
    float v = (k < 512) ? U[o * 512 + k] : W[o * 512 + (k - 512)];
    Wcat[idx] = f2bf(v);
}

// ---- persistent recurrence, 128 WGs ----
// WG (g = bid>>5: 16 batches, s = bid&31: 64 gate-rows = 16 ocols)
// 8 waves = (mp 0..3: 16 rows) x (kh 0..1: 256-wide K-half of h)
// U-weights resident (32 VGPR/wave); x-part streamed off critical path into SpX ring.
__launch_bounds__(512, 2)
__global__ void lstm_rec(const unsigned short* __restrict__ Xb,
                         const unsigned short* __restrict__ Wcat,
                         unsigned short* __restrict__ hbuf,   // [2][64][512] bf16
                         unsigned int* __restrict__ cnt,      // [NGRP][T_]
                         float* __restrict__ out,             // H then C (fp32)
                         const float* __restrict__ bi, const float* __restrict__ bc,
                         const float* __restrict__ bo, const float* __restrict__ bUf,
                         const float* __restrict__ bUc, const float* __restrict__ bUo) {
    __shared__ float SpH[2][4][16][20];      // h-half partials from kh=1 (parity-buffered)
    __shared__ float SpX[2][4][2][16][20];   // x partials ring [slot][mp][kh][batch][4 gates x q]
    __shared__ unsigned int wcnt;            // monotonic kh0-wave completions
    __shared__ int go;                       // broadcast: step t may proceed

    const int tid  = threadIdx.x;
    const int bid  = blockIdx.x;
    const int g    = bid >> 5;
    const int s    = bid & 31;
    const int wave = tid >> 6;
    const int lane = tid & 63;
    const int mp   = wave >> 1;
    const int kh   = wave & 1;
    const int q    = lane >> 4;
    const int bl   = lane & 15;

    if (tid == 0) { wcnt = 0u; go = 0; }

    // ---- resident U fragments: 16 rows x 256 K = 8 x short8 = 32 VGPRs ----
    const int r0 = s * 64 + mp * 16;
    const unsigned short* wrow  = Wcat + (size_t)(r0 + bl) * KF + kh * 256 + q * 8;
    const unsigned short* wxrow = wrow + 512;    // x-part of same rows/K-offsets
    short8 Uf8[8];
    #pragma unroll
    for (int kt = 0; kt < 8; ++kt) Uf8[kt] = *(const short8*)(wrow + kt * 32);

    // ---- per-lane gate identity (kh==0): ocol og, batch g*16+bl ----
    const int og = s * 16 + mp * 4 + q;
    const float bi0 = bi[og],              bf0 = bi[og] + bUf[og];
    const float bc0 = bc[og] + bUc[og],    bo0 = bo[og] + bUo[og];
    float cst = 0.f;

    const unsigned short* xbl = Xb + (size_t)(g * GB + bl) * T_ * D_ + kh * 256 + q * 8;
    unsigned int* gfl = cnt + (size_t)g * T_;
    float* Hout = out;
    float* Cout = out + (size_t)B_ * T_ * D_;

    // ---- prologue: x-partial for t=0 into SpX[0] ----
    {
        f32x4 ax = {0.f, 0.f, 0.f, 0.f};
        #pragma unroll
        for (int kt = 0; kt < 8; ++kt) {
            short8 wx = *(const short8*)(wxrow + kt * 32);
            short8 xv = *(const short8*)(xbl + kt * 32);
            ax = __builtin_amdgcn_mfma_f32_16x16x32_bf16(wx, xv, ax, 0, 0, 0);
        }
        *(f32x4*)&SpX[0][mp][kh][bl][4 * q] = ax;
    }
    __syncthreads();

    for (int t = 0; t < T_; ++t) {
        const int slot = t & 1;

        // ---- a) wait for h_{t-1}: one poller, LDS broadcast ----
        if (t > 0) {
            if (wave == 0) {
                if (lane == 0) {
                    while (__hip_atomic_load(gfl + (t - 1), __ATOMIC_RELAXED, __HIP_MEMORY_SCOPE_AGENT) < NSLC) { }
                    __hip_atomic_store(&go, t, __ATOMIC_RELAXED, __HIP_MEMORY_SCOPE_WORKGROUP);
                }
            } else if (lane == 0) {
                while (__hip_atomic_load(&go, __ATOMIC_RELAXED, __HIP_MEMORY_SCOPE_WORKGROUP) < t) { }
            }
            asm volatile("" ::: "memory");
        }

        // ---- b) h-half MFMAs: direct coherent B-frag loads, 2 acc chains ----
        const unsigned long long* hp = (const unsigned long long*)
            (hbuf + ((size_t)(slot ^ 1) * B_ + g * GB + bl) * D_ + kh * 256 + q * 8);
        f32x4 aE = {0.f, 0.f, 0.f, 0.f}, aO = {0.f, 0.f, 0.f, 0.f};
        #pragma unroll
        for (int kt = 0; kt < 8; kt += 2) {
            union { unsigned long long u[2]; short8 v; } c0, c1;
            c0.u[0] = __hip_atomic_load(hp + kt * 8,     __ATOMIC_RELAXED, __HIP_MEMORY_SCOPE_AGENT);
            c0.u[1] = __hip_atomic_load(hp + kt * 8 + 1, __ATOMIC_RELAXED, __HIP_MEMORY_SCOPE_AGENT);
            c1.u[0] = __hip_atomic_load(hp + kt * 8 + 8, __ATOMIC_RELAXED, __HIP_MEMORY_SCOPE_AGENT);
            c1.u[1] = __hip_atomic_load(hp + kt * 8 + 9, __ATOMIC_RELAXED, __HIP_MEMORY_SCOPE_AGENT);
            aE = __builtin_amdgcn_mfma_f32_16x16x32_bf16(Uf8[kt],     c0.v, aE, 0, 0, 0);
            aO = __builtin_amdgcn_mfma_f32_16x16x32_bf16(Uf8[kt + 1], c1.v, aO, 0, 0, 0);
        }
        f32x4 accH = aE + aO;

        // ---- c) kh=1 publishes its h-partial ----
        if (kh == 1) *(f32x4*)&SpH[slot][mp][bl][4 * q] = accH;
        __syncthreads();   // d) orders: SpH/SpX reads below vs next writes

        // ---- e) kh=0: merge + gates + h store + flag ----
        float hv = 0.f, cv = 0.f;
        if (kh == 0) {
            f32x4 A = accH;
            A += *(const f32x4*)&SpH[slot][mp][bl][4 * q];
            A += *(const f32x4*)&SpX[slot][mp][0][bl][4 * q];
            A += *(const f32x4*)&SpX[slot][mp][1][bl][4 * q];
            float iv = sigmf(A[0] + bi0);
            float fv = sigmf(A[1] + bf0);
            float cc = tanh_f(A[2] + bc0);
            float ov = sigmf(A[3] + bo0);
            cv = fv * cst + iv * cc;
            hv = ov * tanh_f(cv);
            cst = cv;
            __hip_atomic_store(hbuf + ((size_t)slot * B_ + g * GB + bl) * D_ + og,
                               f2bf(hv), __ATOMIC_RELAXED, __HIP_MEMORY_SCOPE_AGENT);
            asm volatile("s_waitcnt vmcnt(0)" ::: "memory");
            if (lane == 0)
                __hip_atomic_fetch_add(&wcnt, 1u, __ATOMIC_RELAXED, __HIP_MEMORY_SCOPE_WORKGROUP);
            if (wave == 0 && lane == 0) {
                while (__hip_atomic_load(&wcnt, __ATOMIC_RELAXED, __HIP_MEMORY_SCOPE_WORKGROUP) < 4u * (unsigned)(t + 1)) { }
                __hip_atomic_fetch_add(gfl + t, 1u, __ATOMIC_RELAXED, __HIP_MEMORY_SCOPE_AGENT);
            }
        }

        // ---- f) x-partial for t+1 (streamed Wx, off critical path) ----
        if (t + 1 < T_) {
            const unsigned short* xp = xbl + (size_t)(t + 1) * D_;
            f32x4 ax = {0.f, 0.f, 0.f, 0.f};
            #pragma unroll
            for (int kt = 0; kt < 8; ++kt) {
                short8 wx = *(const short8*)(wxrow + kt * 32);
                short8 xv = *(const short8*)(xp + kt * 32);
                ax = __builtin_amdgcn_mfma_f32_16x16x32_bf16(wx, xv, ax, 0, 0, 0);
            }
            *(f32x4*)&SpX[slot ^ 1][mp][kh][bl][4 * q] = ax;
        }

        // ---- streaming outputs, off the flag path ----
        if (kh == 0) {
            const size_t oi = ((size_t)(g * GB + bl) * T_ + t) * D_ + og;
            __builtin_nontemporal_store(hv, Hout + oi);
            __builtin_nontemporal_store(cv, Cout + oi);
        }
    }
}

extern "C" void kernel_launch(void* const* d_in, const int* in_sizes, int n_in,
                              void* d_out, int out_size, void* d_ws, size_t ws_size,
                              hipStream_t stream) {
    const float* X   = (const float*)d_in[0];
    const float* Wi  = (const float*)d_in[1];
    const float* bi  = (const float*)d_in[2];
    // d_in[3] = Wf, d_in[4] = bf : unused by reference semantics
    const float* Wc  = (const float*)d_in[5];
    const float* bc  = (const float*)d_in[6];
    const float* Wo  = (const float*)d_in[7];
    const float* bo  = (const float*)d_in[8];
    const float* Ui  = (const float*)d_in[9];
    const float* Uf  = (const float*)d_in[10];
    const float* bUf = (const float*)d_in[11];
    const float* Uc  = (const float*)d_in[12];
    const float* bUc = (const float*)d_in[13];
    const float* Uo  = (const float*)d_in[14];
    const float* bUo = (const float*)d_in[15];

    char* ws = (char*)d_ws;
    const size_t XB_BYTES   = (size_t)B_ * T_ * D_ * 2;   // 33,554,432
    const size_t WCAT_BYTES = (size_t)2048 * 1024 * 2;    //  4,194,304
    const size_t HBUF_BYTES = (size_t)2 * B_ * D_ * 2;    //    131,072 (bf16)
    const size_t CNT_BYTES  = (size_t)NGRP * T_ * 4;      //      8,192

    unsigned short* Xb   = (unsigned short*)ws;
    unsigned short* Wcat = (unsigned short*)(ws + XB_BYTES);
    unsigned short* hbuf = (unsigned short*)(ws + XB_BYTES + WCAT_BYTES);
    unsigned int*   cnt  = (unsigned int*)(ws + XB_BYTES + WCAT_BYTES + HBUF_BYTES);

    // zero h (t=0 reads slot 1) and the per-step flags, every call
    hipMemsetAsync(hbuf, 0, HBUF_BYTES + CNT_BYTES, stream);

    prep_x<<<2048, 256, 0, stream>>>(X, Xb, B_ * T_ * D_ / 4);
    prep_w<<<8192, 256, 0, stream>>>(Wi, Wc, Wo, Ui, Uf, Uc, Uo, Wcat);
    lstm_rec<<<NGRP * NSLC, 512, 0, stream>>>(Xb, Wcat, hbuf, cnt, (float*)d_out,
                                              bi, bc, bo, bUf, bUc, bUo);
}

// Round 5
// 3002.127 us; speedup vs baseline: 1.2587x; 1.1093x over previous
//
#include <hip/hip_runtime.h>

#define B_    64
#define T_    512
#define D_    512
#define KF    1024      // fused weight K = [h(512) ; x(512)]
#define NGRP  4         // batch groups
#define NSLC  16        // WG slices per group
#define GB    16        // batches per group

using short8 = __attribute__((ext_vector_type(8))) short;
using f32x4  = __attribute__((ext_vector_type(4))) float;

__device__ __forceinline__ unsigned short f2bf(float f) {
    unsigned int u = __float_as_uint(f);
    u = (u + 0x7fffu + ((u >> 16) & 1u)) >> 16;
    return (unsigned short)u;
}
__device__ __forceinline__ float sigmf(float x)  { return 1.0f / (1.0f + __expf(-x)); }
__device__ __forceinline__ float tanh_f(float x) { return 1.0f - 2.0f / (1.0f + __expf(2.0f * x)); }

// ---- prep: X fp32 -> bf16 ----
__global__ void prep_x(const float* __restrict__ X, unsigned short* __restrict__ Xb, int n4) {
    int stride = gridDim.x * blockDim.x;
    for (int i = blockIdx.x * blockDim.x + threadIdx.x; i < n4; i += stride) {
        float4 v = ((const float4*)X)[i];
        ushort4 o;
        o.x = f2bf(v.x); o.y = f2bf(v.y); o.z = f2bf(v.z); o.w = f2bf(v.w);
        ((ushort4*)Xb)[i] = o;
    }
}

// ---- prep: fused weight Wcat[r = o*4+g][k]; gate g: 0=i(Ui,Wi) 1=f(Uf,Wi quirk) 2=c(Uc,Wc) 3=o(Uo,Wo)
__global__ void prep_w(const float* __restrict__ Wi, const float* __restrict__ Wc,
                       const float* __restrict__ Wo,
                       const float* __restrict__ Ui, const float* __restrict__ Uf,
                       const float* __restrict__ Uc, const float* __restrict__ Uo,
                       unsigned short* __restrict__ Wcat) {
    int idx = blockIdx.x * blockDim.x + threadIdx.x;
    if (idx >= 2048 * 1024) return;
    int r = idx >> 10, k = idx & 1023;
    int o = r >> 2, g = r & 3;
    const float* U = (g == 0) ? Ui : (g == 1) ? Uf : (g == 2) ? Uc : Uo;
    const float* W = (g < 2) ? Wi : (g == 2) ? Wc : Wo;
    float v = (k < 512) ? U[o * 512 + k] : W[o * 512 + (k - 512)];
    Wcat[idx] = f2bf(v);
}

// ---- persistent recurrence, 64 WGs (1/CU, 8 waves = 2/SIMD -> 256 VGPR budget) ----
// WG (g = bid>>4: 16 batches, s = bid&15: 128 gate-rows = 32 ocols)
// wave w (0..7) owns gate-rows s*128 + w*16 .. +15, FULL K=1024 resident in VGPRs.
// Lane (q=lane>>4, bl=lane&15): D-frag = 4 gates of (ocol s*32+w*4+q, batch bl). No cross-wave reduce.
__launch_bounds__(512)
__global__ void lstm_rec(const unsigned short* __restrict__ Xb,
                         const unsigned short* __restrict__ Wcat,
                         unsigned short* __restrict__ hbuf,   // [2][64][512] bf16
                         unsigned int* __restrict__ hflag,    // [NGRP*NSLC] padded x16 dwords
                         float* __restrict__ out,             // H then C (fp32)
                         const float* __restrict__ bi, const float* __restrict__ bc,
                         const float* __restrict__ bo, const float* __restrict__ bUf,
                         const float* __restrict__ bUc, const float* __restrict__ bUo) {
    __shared__ unsigned char Hl[16 * 1024];   // h tile [16 b][512] bf16, XOR-swizzled

    const int tid  = threadIdx.x;
    const int bid  = blockIdx.x;
    const int g    = bid >> 4;
    const int s    = bid & 15;
    const int wave = tid >> 6;
    const int lane = tid & 63;
    const int q    = lane >> 4;
    const int bl   = lane & 15;

    // ---- resident fused weights: 16 rows x 1024 K = 32 x short8 = 128 VGPRs ----
    const unsigned short* wrow = Wcat + (size_t)(s * 128 + wave * 16 + bl) * KF + q * 8;
    short8 Uh[16], Ux[16];
    #pragma unroll
    for (int kt = 0; kt < 16; ++kt) Uh[kt] = *(const short8*)(wrow + kt * 32);
    #pragma unroll
    for (int kt = 0; kt < 16; ++kt) Ux[kt] = *(const short8*)(wrow + 512 + kt * 32);

    // ---- per-lane gate identity: ocol og, batch g*16+bl ----
    const int og = s * 32 + wave * 4 + q;
    const float bi0 = bi[og],           bf0 = bi[og] + bUf[og];
    const float bc0 = bc[og] + bUc[og], bo0 = bo[og] + bUo[og];
    float cst = 0.f;

    // ---- staging identity: thread (sb=batch, seg=16-col chunk) ----
    const int sb  = tid >> 5;
    const int seg = tid & 31;
    const int sx  = (sb & 7) << 4;
    unsigned int* pollp = hflag + (size_t)(g * NSLC + (seg >> 1)) * 16;
    unsigned int* myfl  = hflag + (size_t)(g * NSLC + s) * 16;

    // ---- x / MFMA-read identities ----
    const unsigned short* xbl = Xb + (size_t)(g * GB + bl) * T_ * D_ + q * 8;
    const int abase = bl * 1024;
    const int axor  = (bl & 7) << 4;
    const int kq16  = q * 16;

    float* Hout = out;
    float* Cout = out + (size_t)B_ * T_ * D_;

    // ---- prologue: x-partial for t=0 (resident Ux, 2 chains) ----
    f32x4 xa0 = {0.f, 0.f, 0.f, 0.f}, xa1 = {0.f, 0.f, 0.f, 0.f};
    #pragma unroll
    for (int kt = 0; kt < 16; kt += 2) {
        short8 b0 = *(const short8*)(xbl + kt * 32);
        short8 b1 = *(const short8*)(xbl + (kt + 1) * 32);
        xa0 = __builtin_amdgcn_mfma_f32_16x16x32_bf16(Ux[kt],     b0, xa0, 0, 0, 0);
        xa1 = __builtin_amdgcn_mfma_f32_16x16x32_bf16(Ux[kt + 1], b1, xa1, 0, 0, 0);
    }

    for (int t = 0; t < T_; ++t) {
        f32x4 ha0 = {0.f, 0.f, 0.f, 0.f}, ha1 = {0.f, 0.f, 0.f, 0.f};

        if (t > 0) {
            // ---- a) poll producer flag (relaxed, LLC-served, no invalidates) ----
            while (__hip_atomic_load(pollp, __ATOMIC_RELAXED, __HIP_MEMORY_SCOPE_AGENT) < (unsigned)t) { }
            asm volatile("" ::: "memory");
            // ---- stage h_{t-1}: 32 B/thread, coherent loads -> swizzled LDS ----
            const unsigned long long* hs = (const unsigned long long*)
                (hbuf + ((size_t)((t + 1) & 1) * B_ + g * GB + sb) * D_ + seg * 16);
            unsigned long long d0 = __hip_atomic_load(hs + 0, __ATOMIC_RELAXED, __HIP_MEMORY_SCOPE_AGENT);
            unsigned long long d1 = __hip_atomic_load(hs + 1, __ATOMIC_RELAXED, __HIP_MEMORY_SCOPE_AGENT);
            unsigned long long d2 = __hip_atomic_load(hs + 2, __ATOMIC_RELAXED, __HIP_MEMORY_SCOPE_AGENT);
            unsigned long long d3 = __hip_atomic_load(hs + 3, __ATOMIC_RELAXED, __HIP_MEMORY_SCOPE_AGENT);
            *(uint4*)(Hl + sb * 1024 + ((seg * 32)      ^ sx)) =
                make_uint4((unsigned)d0, (unsigned)(d0 >> 32), (unsigned)d1, (unsigned)(d1 >> 32));
            *(uint4*)(Hl + sb * 1024 + ((seg * 32 + 16) ^ sx)) =
                make_uint4((unsigned)d2, (unsigned)(d2 >> 32), (unsigned)d3, (unsigned)(d3 >> 32));
            __syncthreads();
            // ---- b) h-MFMAs from LDS, 2 chains ----
            #pragma unroll
            for (int kt = 0; kt < 16; kt += 2) {
                short8 a0 = *(const short8*)(Hl + abase + ((kq16 + kt * 64)       ^ axor));
                short8 a1 = *(const short8*)(Hl + abase + ((kq16 + (kt + 1) * 64) ^ axor));
                ha0 = __builtin_amdgcn_mfma_f32_16x16x32_bf16(Uh[kt],     a0, ha0, 0, 0, 0);
                ha1 = __builtin_amdgcn_mfma_f32_16x16x32_bf16(Uh[kt + 1], a1, ha1, 0, 0, 0);
            }
        }

        // ---- c) merge + gates (all in-register; D-frag = 4 gates of (og, bl)) ----
        f32x4 A = (ha0 + ha1) + (xa0 + xa1);
        float iv = sigmf(A[0] + bi0);
        float fv = sigmf(A[1] + bf0);
        float cc = tanh_f(A[2] + bc0);
        float ov = sigmf(A[3] + bo0);
        float cv = fv * cst + iv * cc;
        float hv = ov * tanh_f(cv);
        cst = cv;

        // ---- d) publish h (bf16 scatter), barrier drains (implicit vmcnt 0), flag ----
        __hip_atomic_store(hbuf + ((size_t)(t & 1) * B_ + g * GB + bl) * D_ + og,
                           f2bf(hv), __ATOMIC_RELAXED, __HIP_MEMORY_SCOPE_AGENT);
        __syncthreads();
        if (tid == 0)
            __hip_atomic_store(myfl, (unsigned)(t + 1), __ATOMIC_RELAXED, __HIP_MEMORY_SCOPE_AGENT);

        // ---- e) x-partial for t+1 (off critical path, resident Ux) ----
        if (t + 1 < T_) {
            const unsigned short* xp = xbl + (size_t)(t + 1) * D_;
            f32x4 n0 = {0.f, 0.f, 0.f, 0.f}, n1 = {0.f, 0.f, 0.f, 0.f};
            #pragma unroll
            for (int kt = 0; kt < 16; kt += 2) {
                short8 b0 = *(const short8*)(xp + kt * 32);
                short8 b1 = *(const short8*)(xp + (kt + 1) * 32);
                n0 = __builtin_amdgcn_mfma_f32_16x16x32_bf16(Ux[kt],     b0, n0, 0, 0, 0);
                n1 = __builtin_amdgcn_mfma_f32_16x16x32_bf16(Ux[kt + 1], b1, n1, 0, 0, 0);
            }
            xa0 = n0; xa1 = n1;
        }

        // ---- f) streaming outputs (plain stores; WG covers full 128-B lines) ----
        const size_t oi = ((size_t)(g * GB + bl) * T_ + t) * D_ + og;
        Hout[oi] = hv;
        Cout[oi] = cv;
    }
}

extern "C" void kernel_launch(void* const* d_in, const int* in_sizes, int n_in,
                              void* d_out, int out_size, void* d_ws, size_t ws_size,
                              hipStream_t stream) {
    const float* X   = (const float*)d_in[0];
    const float* Wi  = (const float*)d_in[1];
    const float* bi  = (const float*)d_in[2];
    // d_in[3] = Wf, d_in[4] = bf : unused by reference semantics
    const float* Wc  = (const float*)d_in[5];
    const float* bc  = (const float*)d_in[6];
    const float* Wo  = (const float*)d_in[7];
    const float* bo  = (const float*)d_in[8];
    const float* Ui  = (const float*)d_in[9];
    const float* Uf  = (const float*)d_in[10];
    const float* bUf = (const float*)d_in[11];
    const float* Uc  = (const float*)d_in[12];
    const float* bUc = (const float*)d_in[13];
    const float* Uo  = (const float*)d_in[14];
    const float* bUo = (const float*)d_in[15];

    char* ws = (char*)d_ws;
    const size_t XB_BYTES   = (size_t)B_ * T_ * D_ * 2;   // 33,554,432
    const size_t WCAT_BYTES = (size_t)2048 * 1024 * 2;    //  4,194,304
    const size_t HBUF_BYTES = (size_t)2 * B_ * D_ * 2;    //    131,072 (bf16)
    const size_t FLAG_BYTES = (size_t)NGRP * NSLC * 16 * 4; //    4,096

    unsigned short* Xb    = (unsigned short*)ws;
    unsigned short* Wcat  = (unsigned short*)(ws + XB_BYTES);
    unsigned short* hbuf  = (unsigned short*)(ws + XB_BYTES + WCAT_BYTES);
    unsigned int*   hflag = (unsigned int*)(ws + XB_BYTES + WCAT_BYTES + HBUF_BYTES);

    // zero h (t=1 reads slot 1) and the per-producer flags, every call
    hipMemsetAsync(hbuf, 0, HBUF_BYTES + FLAG_BYTES, stream);

    prep_x<<<2048, 256, 0, stream>>>(X, Xb, B_ * T_ * D_ / 4);
    prep_w<<<8192, 256, 0, stream>>>(Wi, Wc, Wo, Ui, Uf, Uc, Uo, Wcat);
    lstm_rec<<<NGRP * NSLC, 512, 0, stream>>>(Xb, Wcat, hbuf, hflag, (float*)d_out,
                                              bi, bc, bo, bUf, bUc, bUo);
}

// Round 6
// 1468.833 us; speedup vs baseline: 2.5727x; 2.0439x over previous
//
#include <hip/hip_runtime.h>

#define B_    64
#define T_    512
#define D_    512
#define KF    1024      // fused weight K = [h(512) ; x(512)]
#define NGRP  4         // batch groups
#define NSLC  16        // WG slices per group
#define GB    16        // batches per group

using short8 = __attribute__((ext_vector_type(8))) short;
using f32x4  = __attribute__((ext_vector_type(4))) float;

__device__ __forceinline__ unsigned short f2bf(float f) {
    unsigned int u = __float_as_uint(f);
    u = (u + 0x7fffu + ((u >> 16) & 1u)) >> 16;
    return (unsigned short)u;
}
__device__ __forceinline__ float sigmf(float x)  { return 1.0f / (1.0f + __expf(-x)); }
__device__ __forceinline__ float tanh_f(float x) { return 1.0f - 2.0f / (1.0f + __expf(2.0f * x)); }

// ---- prep: X fp32 -> bf16 ----
__global__ void prep_x(const float* __restrict__ X, unsigned short* __restrict__ Xb, int n4) {
    int stride = gridDim.x * blockDim.x;
    for (int i = blockIdx.x * blockDim.x + threadIdx.x; i < n4; i += stride) {
        float4 v = ((const float4*)X)[i];
        ushort4 o;
        o.x = f2bf(v.x); o.y = f2bf(v.y); o.z = f2bf(v.z); o.w = f2bf(v.w);
        ((ushort4*)Xb)[i] = o;
    }
}

// ---- prep: fused weight Wcat[r = o*4+g][k]; gate g: 0=i(Ui,Wi) 1=f(Uf,Wi quirk) 2=c(Uc,Wc) 3=o(Uo,Wo)
__global__ void prep_w(const float* __restrict__ Wi, const float* __restrict__ Wc,
                       const float* __restrict__ Wo,
                       const float* __restrict__ Ui, const float* __restrict__ Uf,
                       const float* __restrict__ Uc, const float* __restrict__ Uo,
                       unsigned short* __restrict__ Wcat) {
    int idx = blockIdx.x * blockDim.x + threadIdx.x;
    if (idx >= 2048 * 1024) return;
    int r = idx >> 10, k = idx & 1023;
    int o = r >> 2, g = r & 3;
    const float* U = (g == 0) ? Ui : (g == 1) ? Uf : (g == 2) ? Uc : Uo;
    const float* W = (g < 2) ? Wi : (g == 2) ? Wc : Wo;
    float v = (k < 512) ? U[o * 512 + k] : W[o * 512 + (k - 512)];
    Wcat[idx] = f2bf(v);
}

// ---- persistent recurrence, 64 WGs (1/CU, 8 waves = EXACTLY 2/SIMD) ----
// WG (g = bid>>4: 16 batches, s = bid&15: 128 gate-rows = 32 ocols)
// wave w owns 16 gate-rows, FULL K=1024 resident in VGPRs (atomic loads: not sinkable).
// Lane (q=lane>>4, bl=lane&15): D-frag = 4 gates of (ocol s*32+w*4+q, batch g*16+bl).
__attribute__((amdgpu_waves_per_eu(2, 2)))
__launch_bounds__(512)
__global__ void lstm_rec(const unsigned short* __restrict__ Xb,
                         const unsigned short* __restrict__ Wcat,
                         unsigned short* __restrict__ hbuf,   // [2][64][512] bf16
                         unsigned int* __restrict__ hflag,    // [NGRP*NSLC] padded x16 dwords
                         float* __restrict__ out,             // H then C (fp32)
                         const float* __restrict__ bi, const float* __restrict__ bc,
                         const float* __restrict__ bo, const float* __restrict__ bUf,
                         const float* __restrict__ bUc, const float* __restrict__ bUo) {
    __shared__ unsigned char Hl[16 * 1024];   // h tile [16 b][512] bf16, XOR-swizzled
    __shared__ unsigned char Xl[16 * 1024];   // x tile for t+1, same layout

    const int tid  = threadIdx.x;
    const int bid  = blockIdx.x;
    const int g    = bid >> 4;
    const int s    = bid & 15;
    const int wave = tid >> 6;
    const int lane = tid & 63;
    const int q    = lane >> 4;
    const int bl   = lane & 15;

    // ---- resident fused weights: 16 rows x 1024 K = 32 x short8 = 128 VGPRs ----
    // atomic 8B loads: LLVM will not rematerialize/sink these into the loop.
    const unsigned short* wrow = Wcat + (size_t)(s * 128 + wave * 16 + bl) * KF + q * 8;
    short8 Uh[16], Ux[16];
    #pragma unroll
    for (int kt = 0; kt < 16; ++kt) {
        union { unsigned long long u[2]; short8 v; } wh, wx;
        const unsigned long long* ph = (const unsigned long long*)(wrow + kt * 32);
        const unsigned long long* px = (const unsigned long long*)(wrow + 512 + kt * 32);
        wh.u[0] = __hip_atomic_load(ph,     __ATOMIC_RELAXED, __HIP_MEMORY_SCOPE_AGENT);
        wh.u[1] = __hip_atomic_load(ph + 1, __ATOMIC_RELAXED, __HIP_MEMORY_SCOPE_AGENT);
        wx.u[0] = __hip_atomic_load(px,     __ATOMIC_RELAXED, __HIP_MEMORY_SCOPE_AGENT);
        wx.u[1] = __hip_atomic_load(px + 1, __ATOMIC_RELAXED, __HIP_MEMORY_SCOPE_AGENT);
        Uh[kt] = wh.v;
        Ux[kt] = wx.v;
    }

    // ---- per-lane gate identity: ocol og, batch g*16+bl ----
    const int og = s * 32 + wave * 4 + q;
    const float bi0 = bi[og],           bf0 = bi[og] + bUf[og];
    const float bc0 = bc[og] + bUc[og], bo0 = bo[og] + bUo[og];
    float cst = 0.f;

    // ---- staging identity: thread (sb=batch, seg=16-col chunk) ----
    const int sb  = tid >> 5;
    const int seg = tid & 31;
    const int sx  = (sb & 7) << 4;
    unsigned int* pollp = hflag + (size_t)(g * NSLC + (seg >> 1)) * 16;
    unsigned int* myfl  = hflag + (size_t)(g * NSLC + s) * 16;
    const unsigned short* xst = Xb + (size_t)(g * GB + sb) * T_ * D_ + seg * 16;

    // ---- MFMA-read constants ----
    const unsigned short* xbl = Xb + (size_t)(g * GB + bl) * T_ * D_ + q * 8;
    const int abase = bl * 1024;
    const int axor  = (bl & 7) << 4;
    const int kq16  = q * 16;

    float* Hout = out;
    float* Cout = out + (size_t)B_ * T_ * D_;

    // ---- prologue: x-partial for t=0 (direct global reads, resident Ux) ----
    f32x4 xa0 = {0.f, 0.f, 0.f, 0.f}, xa1 = {0.f, 0.f, 0.f, 0.f};
    #pragma unroll
    for (int kt = 0; kt < 16; kt += 2) {
        short8 b0 = *(const short8*)(xbl + kt * 32);
        short8 b1 = *(const short8*)(xbl + (kt + 1) * 32);
        xa0 = __builtin_amdgcn_mfma_f32_16x16x32_bf16(Ux[kt],     b0, xa0, 0, 0, 0);
        xa1 = __builtin_amdgcn_mfma_f32_16x16x32_bf16(Ux[kt + 1], b1, xa1, 0, 0, 0);
    }

    for (int t = 0; t < T_; ++t) {
        // ---- x prefetch for t+1 (overlaps poll + h load) ----
        uint4 xr0, xr1;
        const bool hasNext = (t + 1 < T_);
        if (hasNext) {
            const uint4* xs = (const uint4*)(xst + (size_t)(t + 1) * D_);
            xr0 = xs[0]; xr1 = xs[1];
        }

        f32x4 ha0 = {0.f, 0.f, 0.f, 0.f}, ha1 = {0.f, 0.f, 0.f, 0.f};
        if (t > 0) {
            // ---- a) poll own producer's flag (relaxed, LLC-served) ----
            while (__hip_atomic_load(pollp, __ATOMIC_RELAXED, __HIP_MEMORY_SCOPE_AGENT) < (unsigned)t) { }
            asm volatile("" ::: "memory");
            // ---- stage h_{t-1}: 32 B/thread -> swizzled LDS ----
            const unsigned long long* hs = (const unsigned long long*)
                (hbuf + ((size_t)((t + 1) & 1) * B_ + g * GB + sb) * D_ + seg * 16);
            unsigned long long d0 = __hip_atomic_load(hs + 0, __ATOMIC_RELAXED, __HIP_MEMORY_SCOPE_AGENT);
            unsigned long long d1 = __hip_atomic_load(hs + 1, __ATOMIC_RELAXED, __HIP_MEMORY_SCOPE_AGENT);
            unsigned long long d2 = __hip_atomic_load(hs + 2, __ATOMIC_RELAXED, __HIP_MEMORY_SCOPE_AGENT);
            unsigned long long d3 = __hip_atomic_load(hs + 3, __ATOMIC_RELAXED, __HIP_MEMORY_SCOPE_AGENT);
            *(uint4*)(Hl + sb * 1024 + ((seg * 32)      ^ sx)) =
                make_uint4((unsigned)d0, (unsigned)(d0 >> 32), (unsigned)d1, (unsigned)(d1 >> 32));
            *(uint4*)(Hl + sb * 1024 + ((seg * 32 + 16) ^ sx)) =
                make_uint4((unsigned)d2, (unsigned)(d2 >> 32), (unsigned)d3, (unsigned)(d3 >> 32));
            __syncthreads();   // barrier1
            // ---- b) h-MFMAs from LDS, 2 chains ----
            #pragma unroll
            for (int kt = 0; kt < 16; kt += 2) {
                short8 a0 = *(const short8*)(Hl + abase + ((kq16 + kt * 64)       ^ axor));
                short8 a1 = *(const short8*)(Hl + abase + ((kq16 + (kt + 1) * 64) ^ axor));
                ha0 = __builtin_amdgcn_mfma_f32_16x16x32_bf16(Uh[kt],     a0, ha0, 0, 0, 0);
                ha1 = __builtin_amdgcn_mfma_f32_16x16x32_bf16(Uh[kt + 1], a1, ha1, 0, 0, 0);
            }
        }

        // ---- c) publish x-tile for t+1 into LDS (ordered by barrier2) ----
        if (hasNext) {
            *(uint4*)(Xl + sb * 1024 + ((seg * 32)      ^ sx)) = xr0;
            *(uint4*)(Xl + sb * 1024 + ((seg * 32 + 16) ^ sx)) = xr1;
        }

        // ---- d) gates (all in-register) ----
        f32x4 A = (ha0 + ha1) + (xa0 + xa1);
        float iv = sigmf(A[0] + bi0);
        float fv = sigmf(A[1] + bf0);
        float cc = tanh_f(A[2] + bc0);
        float ov = sigmf(A[3] + bo0);
        float cv = fv * cst + iv * cc;
        float hv = ov * tanh_f(cv);
        cst = cv;

        // ---- e) publish h (bf16 scatter), barrier2 drains stores, flag ----
        __hip_atomic_store(hbuf + ((size_t)(t & 1) * B_ + g * GB + bl) * D_ + og,
                           f2bf(hv), __ATOMIC_RELAXED, __HIP_MEMORY_SCOPE_AGENT);
        __syncthreads();   // barrier2: drains h stores (vmcnt 0), orders Xl
        if (tid == 0)
            __hip_atomic_store(myfl, (unsigned)(t + 1), __ATOMIC_RELAXED, __HIP_MEMORY_SCOPE_AGENT);

        // ---- f) x-partial for t+1 from LDS (off critical path) ----
        if (hasNext) {
            f32x4 n0 = {0.f, 0.f, 0.f, 0.f}, n1 = {0.f, 0.f, 0.f, 0.f};
            #pragma unroll
            for (int kt = 0; kt < 16; kt += 2) {
                short8 b0 = *(const short8*)(Xl + abase + ((kq16 + kt * 64)       ^ axor));
                short8 b1 = *(const short8*)(Xl + abase + ((kq16 + (kt + 1) * 64) ^ axor));
                n0 = __builtin_amdgcn_mfma_f32_16x16x32_bf16(Ux[kt],     b0, n0, 0, 0, 0);
                n1 = __builtin_amdgcn_mfma_f32_16x16x32_bf16(Ux[kt + 1], b1, n1, 0, 0, 0);
            }
            xa0 = n0; xa1 = n1;
        }

        // ---- g) streaming outputs (plain stores; WG covers full 128-B lines) ----
        const size_t oi = ((size_t)(g * GB + bl) * T_ + t) * D_ + og;
        Hout[oi] = hv;
        Cout[oi] = cv;
    }
}

extern "C" void kernel_launch(void* const* d_in, const int* in_sizes, int n_in,
                              void* d_out, int out_size, void* d_ws, size_t ws_size,
                              hipStream_t stream) {
    const float* X   = (const float*)d_in[0];
    const float* Wi  = (const float*)d_in[1];
    const float* bi  = (const float*)d_in[2];
    // d_in[3] = Wf, d_in[4] = bf : unused by reference semantics
    const float* Wc  = (const float*)d_in[5];
    const float* bc  = (const float*)d_in[6];
    const float* Wo  = (const float*)d_in[7];
    const float* bo  = (const float*)d_in[8];
    const float* Ui  = (const float*)d_in[9];
    const float* Uf  = (const float*)d_in[10];
    const float* bUf = (const float*)d_in[11];
    const float* Uc  = (const float*)d_in[12];
    const float* bUc = (const float*)d_in[13];
    const float* Uo  = (const float*)d_in[14];
    const float* bUo = (const float*)d_in[15];

    char* ws = (char*)d_ws;
    const size_t XB_BYTES   = (size_t)B_ * T_ * D_ * 2;   // 33,554,432
    const size_t WCAT_BYTES = (size_t)2048 * 1024 * 2;    //  4,194,304
    const size_t HBUF_BYTES = (size_t)2 * B_ * D_ * 2;    //    131,072 (bf16)
    const size_t FLAG_BYTES = (size_t)NGRP * NSLC * 16 * 4; //    4,096

    unsigned short* Xb    = (unsigned short*)ws;
    unsigned short* Wcat  = (unsigned short*)(ws + XB_BYTES);
    unsigned short* hbuf  = (unsigned short*)(ws + XB_BYTES + WCAT_BYTES);
    unsigned int*   hflag = (unsigned int*)(ws + XB_BYTES + WCAT_BYTES + HBUF_BYTES);

    // zero h and the per-producer flags, every call
    hipMemsetAsync(hbuf, 0, HBUF_BYTES + FLAG_BYTES, stream);

    prep_x<<<2048, 256, 0, stream>>>(X, Xb, B_ * T_ * D_ / 4);
    prep_w<<<8192, 256, 0, stream>>>(Wi, Wc, Wo, Ui, Uf, Uc, Uo, Wcat);
    lstm_rec<<<NGRP * NSLC, 512, 0, stream>>>(Xb, Wcat, hbuf, hflag, (float*)d_out,
                                              bi, bc, bo, bUf, bUc, bUo);
}